// Round 2
// baseline (491.697 us; speedup 1.0000x reference)
//
#include <hip/hip_runtime.h>
#include <stdint.h>

// Problem constants (BERTNED): B=64, N=512, L=768, M=24, K=30, H=1024
#define B_   64
#define N_   512
#define L_   768
#define M_   24
#define K_   30
#define H_   1024
#define L2_  1536   // 2*L

// ---------------------------------------------------------------------------
// Kernel 0: detect whether the (B,M,K) boolean mask arrived byte-packed
// (np.bool_, 1 byte/elem) or widened to 4 bytes (int32 0/1 or f32 0.0/1.0).
// We read only the first B*M*K bytes (= 11520 u32 words), which is in-bounds
// under every interpretation. int32 encoding only yields words {0,1}; f32
// only {0, 0x3F800000}; a byte-packed 10%-ones array almost surely yields
// other words (e.g. 0x00010000). flag!=0  =>  byte-packed.
// ---------------------------------------------------------------------------
__global__ void detect_mask_kernel(const uint32_t* __restrict__ mw,
                                   int* __restrict__ flag) {
    __shared__ int f;
    if (threadIdx.x == 0) f = 0;
    __syncthreads();
    int local = 0;
    const int nw = (B_ * M_ * K_) / 4;  // 11520 words = 46080 bytes
    for (int i = threadIdx.x; i < nw; i += blockDim.x) {
        uint32_t v = mw[i];
        if (v != 0u && v != 1u && v != 0x3F800000u) local = 1;
    }
    if (local) f = 1;              // benign same-value race
    __syncthreads();
    if (threadIdx.x == 0) *flag = f;
}

// ---------------------------------------------------------------------------
// Kernel 1: fused span-gather + linear:  alias[bm][h] = sum_l pair[bm][l]*W[l][h] + b[h]
// pair[bm][l] = (l<768 ? sent[b, sidx[bm], l] : sent[b, eidx[bm], l-768]), 0 if idx==-1
// f32 vector GEMM, 64x64 tile, BK=16, 4x4 register blocking, 256 threads.
// ---------------------------------------------------------------------------
__global__ __launch_bounds__(256) void span_gemm_kernel(
    const float* __restrict__ sent,
    const int*   __restrict__ sidx,
    const int*   __restrict__ eidx,
    const float* __restrict__ W,
    const float* __restrict__ bias,
    float*       __restrict__ alias_out) {

    __shared__ float As[16][64];   // [local k][row]  (transposed for float4 reads)
    __shared__ float Bs[16][64];   // [local k][col]
    __shared__ int   offS[64];
    __shared__ int   offE[64];

    const int tid = threadIdx.x;
    const int bm0 = blockIdx.y * 64;   // row-tile base in [0, 1536)
    const int h0  = blockIdx.x * 64;   // col-tile base in [0, 1024)

    if (tid < 64) {
        const int bm = bm0 + tid;
        const int b  = bm / M_;
        const int si = sidx[bm];
        const int ei = eidx[bm];
        offS[tid] = (si < 0) ? -1 : (b * N_ + si) * L_;
        offE[tid] = (ei < 0) ? -1 : (b * N_ + ei) * L_;
    }
    __syncthreads();

    float acc[4][4] = {};

    const int ar  = tid >> 2;         // 0..63 : A row
    const int akq = (tid & 3) * 4;    // 0,4,8,12 : A local-k base (float4 span)
    const int bkr = tid >> 4;         // 0..15 : B local k
    const int bc  = (tid & 15) * 4;   // B col base
    const int ty  = tid >> 4;         // 0..15 : compute row group
    const int tx  = tid & 15;         // 0..15 : compute col group

    for (int l0 = 0; l0 < L2_; l0 += 16) {
        // ---- stage A (gathered, 64 rows x 16 k) ----
        {
            const int lb = l0 + akq;              // global l of first elem; 4-chunk
            int off, ll;                          // never straddles l=768 (768%4==0)
            if (lb < L_) { off = offS[ar]; ll = lb; }
            else         { off = offE[ar]; ll = lb - L_; }
            float4 v;
            if (off < 0) v = make_float4(0.f, 0.f, 0.f, 0.f);
            else         v = *reinterpret_cast<const float4*>(sent + off + ll);
            As[akq + 0][ar] = v.x;
            As[akq + 1][ar] = v.y;
            As[akq + 2][ar] = v.z;
            As[akq + 3][ar] = v.w;
        }
        // ---- stage B (16 k x 64 cols) ----
        {
            const float4 v = *reinterpret_cast<const float4*>(
                W + (size_t)(l0 + bkr) * H_ + h0 + bc);
            *reinterpret_cast<float4*>(&Bs[bkr][bc]) = v;
        }
        __syncthreads();

#pragma unroll
        for (int k = 0; k < 16; ++k) {
            const float4 av = *reinterpret_cast<const float4*>(&As[k][ty * 4]);
            const float4 bv = *reinterpret_cast<const float4*>(&Bs[k][tx * 4]);
            acc[0][0] += av.x * bv.x; acc[0][1] += av.x * bv.y;
            acc[0][2] += av.x * bv.z; acc[0][3] += av.x * bv.w;
            acc[1][0] += av.y * bv.x; acc[1][1] += av.y * bv.y;
            acc[1][2] += av.y * bv.z; acc[1][3] += av.y * bv.w;
            acc[2][0] += av.z * bv.x; acc[2][1] += av.z * bv.y;
            acc[2][2] += av.z * bv.z; acc[2][3] += av.z * bv.w;
            acc[3][0] += av.w * bv.x; acc[3][1] += av.w * bv.y;
            acc[3][2] += av.w * bv.z; acc[3][3] += av.w * bv.w;
        }
        __syncthreads();
    }

    // ---- epilogue: add bias, store float4 per row ----
    const float4 bb = *reinterpret_cast<const float4*>(bias + h0 + tx * 4);
#pragma unroll
    for (int i = 0; i < 4; ++i) {
        const int bm = bm0 + ty * 4 + i;
        const float4 o = make_float4(acc[i][0] + bb.x, acc[i][1] + bb.y,
                                     acc[i][2] + bb.z, acc[i][3] + bb.w);
        *reinterpret_cast<float4*>(alias_out + (size_t)bm * H_ + h0 + tx * 4) = o;
    }
}

// ---------------------------------------------------------------------------
// Kernel 2: masked ent copy + scores.  One block per (b,m,k) row of H=1024.
// Each of 256 threads handles one float4.  Memory-bound: ~378 MB HBM.
// ---------------------------------------------------------------------------
__global__ __launch_bounds__(256) void ent_scores_kernel(
    const float* __restrict__ ent_in,
    const float* __restrict__ alias,
    const void*  __restrict__ mask,
    const int*   __restrict__ flag,
    float*       __restrict__ scores,
    float*       __restrict__ ent_out) {

    const int bmk = blockIdx.x;
    const int tid = threadIdx.x;

    const bool byte_packed = (*flag != 0);
    bool masked;
    if (byte_packed) masked = ((const uint8_t*)mask)[bmk] != 0;
    else             masked = ((const uint32_t*)mask)[bmk] != 0u;

    const size_t rowo = (size_t)bmk * H_;
    float p = 0.f;
    float4 e;
    if (masked) {
        e = make_float4(0.f, 0.f, 0.f, 0.f);
    } else {
        e = *reinterpret_cast<const float4*>(ent_in + rowo + tid * 4);
        const int bm = bmk / K_;
        const float4 a = *reinterpret_cast<const float4*>(
            alias + (size_t)bm * H_ + tid * 4);
        p = a.x * e.x + a.y * e.y + a.z * e.z + a.w * e.w;
    }
    *reinterpret_cast<float4*>(ent_out + rowo + tid * 4) = e;

    // block reduction: wave64 shuffle, then cross-wave via LDS
#pragma unroll
    for (int off = 32; off > 0; off >>= 1) p += __shfl_down(p, off);
    __shared__ float red[4];
    if ((tid & 63) == 0) red[tid >> 6] = p;
    __syncthreads();
    if (tid == 0) scores[bmk] = red[0] + red[1] + red[2] + red[3];
}

// ---------------------------------------------------------------------------
extern "C" void kernel_launch(void* const* d_in, const int* in_sizes, int n_in,
                              void* d_out, int out_size, void* d_ws, size_t ws_size,
                              hipStream_t stream) {
    const float* sent = (const float*)d_in[0];   // (B,N,L) f32
    const float* ent  = (const float*)d_in[1];   // (B,M,K,H) f32
    const void*  mask = d_in[2];                 // (B,M,K) bool (width detected)
    const int*   sidx = (const int*)d_in[3];     // (B,M) i32
    const int*   eidx = (const int*)d_in[4];     // (B,M) i32
    const float* W    = (const float*)d_in[5];   // (2L,H) f32
    const float* bias = (const float*)d_in[6];   // (H,) f32

    float* scores  = (float*)d_out;                          // B*M*K
    float* ent_out = (float*)d_out + (size_t)B_ * M_ * K_;   // B*M*K*H

    // workspace layout: [0..4): mask-width flag; [256..): alias_emb (1536x1024 f32)
    int*   flag  = (int*)d_ws;
    float* alias = (float*)((char*)d_ws + 256);

    detect_mask_kernel<<<1, 256, 0, stream>>>((const uint32_t*)mask, flag);

    span_gemm_kernel<<<dim3(H_ / 64, (B_ * M_) / 64), 256, 0, stream>>>(
        sent, sidx, eidx, W, bias, alias);

    ent_scores_kernel<<<B_ * M_ * K_, 256, 0, stream>>>(
        ent, alias, mask, flag, scores, ent_out);
}

// Round 4
// 419.798 us; speedup vs baseline: 1.1713x; 1.1713x over previous
//
#include <hip/hip_runtime.h>
#include <stdint.h>

// Problem constants (BERTNED): B=64, N=512, L=768, M=24, K=30, H=1024
#define B_   64
#define N_   512
#define L_   768
#define M_   24
#define K_   30
#define H_   1024
#define L2_  1536   // 2*L
#define BM_  (B_ * M_)      // 1536 rows of the span GEMM
#define BMK_ (B_ * M_ * K_) // 46080

typedef __attribute__((ext_vector_type(8))) short bf16x8;
typedef __attribute__((ext_vector_type(4))) float f32x4;

// round-to-nearest-even f32 -> bf16 (as raw ushort)
__device__ __forceinline__ ushort f2bf(float f) {
    union { float f; uint32_t u; } v; v.f = f;
    uint32_t u = v.u + 0x7FFFu + ((v.u >> 16) & 1u);
    return (ushort)(u >> 16);
}

// ---------------------------------------------------------------------------
// Kernel 0: detect mask element width (byte-packed bool vs 4-byte 0/1 or f32).
// Reads first B*M*K bytes as u32 words (in-bounds for every interpretation).
// Any word not in {0, 1, 0x3F800000} proves byte packing.
// ---------------------------------------------------------------------------
__global__ void detect_mask_kernel(const uint32_t* __restrict__ mw,
                                   int* __restrict__ flag) {
    __shared__ int f;
    if (threadIdx.x == 0) f = 0;
    __syncthreads();
    int local = 0;
    const int nw = BMK_ / 4;  // 11520 words = 46080 bytes
    for (int i = threadIdx.x; i < nw; i += blockDim.x) {
        uint32_t v = mw[i];
        if (v != 0u && v != 1u && v != 0x3F800000u) local = 1;
    }
    if (local) f = 1;              // benign same-value race
    __syncthreads();
    if (threadIdx.x == 0) *flag = f;
}

// ---------------------------------------------------------------------------
// Prep A: gather span pair rows -> bf16, row-major [BM][2L] (K-contiguous).
// One block per bm row; 192 threads x 8 elems (two float4 -> one 16B store).
// ---------------------------------------------------------------------------
__global__ __launch_bounds__(192) void gather_pair_bf16(
    const float* __restrict__ sent,
    const int*   __restrict__ sidx,
    const int*   __restrict__ eidx,
    ushort*      __restrict__ pairB) {

    const int bm = blockIdx.x;
    const int t  = threadIdx.x;
    const int l  = t * 8;                 // 0..1528, never straddles 768
    const int b  = bm / M_;

    int idx, ll;
    if (l < L_) { idx = sidx[bm]; ll = l; }
    else        { idx = eidx[bm]; ll = l - L_; }

    float4 v0 = make_float4(0.f, 0.f, 0.f, 0.f), v1 = v0;
    if (idx >= 0) {
        const float* src = sent + ((size_t)(b * N_ + idx)) * L_ + ll;
        v0 = *reinterpret_cast<const float4*>(src);
        v1 = *reinterpret_cast<const float4*>(src + 4);
    }
    ushort o[8] = { f2bf(v0.x), f2bf(v0.y), f2bf(v0.z), f2bf(v0.w),
                    f2bf(v1.x), f2bf(v1.y), f2bf(v1.z), f2bf(v1.w) };
    *reinterpret_cast<uint4*>(pairB + (size_t)bm * L2_ + l) =
        *reinterpret_cast<const uint4*>(o);
}

// ---------------------------------------------------------------------------
// Prep B: W[2L][H] f32  ->  Wt[H][2L] bf16 (transposed so B-fragments are
// K-contiguous).  32x32 tiles through LDS.
// ---------------------------------------------------------------------------
__global__ __launch_bounds__(256) void wt_bf16_kernel(
    const float* __restrict__ W, ushort* __restrict__ Wt) {

    __shared__ ushort tile[32][33];
    const int l0 = blockIdx.x * 32;   // K (2L) tile base
    const int h0 = blockIdx.y * 32;   // H tile base
    const int t  = threadIdx.x;

    {   // load 32 rows x 32 cols, convert to bf16 in LDS
        const int r  = t >> 3;
        const int c4 = (t & 7) * 4;
        const float4 v = *reinterpret_cast<const float4*>(
            W + (size_t)(l0 + r) * H_ + h0 + c4);
        tile[r][c4 + 0] = f2bf(v.x);
        tile[r][c4 + 1] = f2bf(v.y);
        tile[r][c4 + 2] = f2bf(v.z);
        tile[r][c4 + 3] = f2bf(v.w);
    }
    __syncthreads();
    {   // store transposed: Wt[h][l], 8B per thread
        const int hr = t >> 3;
        const int l4 = (t & 7) * 4;
        ushort4 o;
        o.x = tile[l4 + 0][hr];
        o.y = tile[l4 + 1][hr];
        o.z = tile[l4 + 2][hr];
        o.w = tile[l4 + 3][hr];
        *reinterpret_cast<ushort4*>(Wt + (size_t)(h0 + hr) * L2_ + l0 + l4) = o;
    }
}

// ---------------------------------------------------------------------------
// MFMA span GEMM: alias[BM][H] = pairB[BM][2L] x Wt[H][2L]^T + bias.
// 1 wave per block, 32x32 output tile (2x2 16x16x32 fragments), fragments
// loaded directly from global (both operands K-contiguous; panels are L2/L3
// resident).  Grid = (H/32, BM/32) = (32, 48) = 1536 blocks.
// C/D mapping (verified m89/m91): col = lane&15, row = (lane>>4)*4 + reg.
// ---------------------------------------------------------------------------
__global__ __launch_bounds__(64) void mfma_span_gemm(
    const ushort* __restrict__ pairB,
    const ushort* __restrict__ WtB,
    const float*  __restrict__ bias,
    float*        __restrict__ alias_out) {

    const int lane = threadIdx.x;
    const int lr = lane & 15;      // fragment row/col index
    const int lg = lane >> 4;      // K-chunk group (8 elems each)
    const int c0 = blockIdx.x * 32;
    const int r0 = blockIdx.y * 32;

    f32x4 acc00 = {}, acc01 = {}, acc10 = {}, acc11 = {};

    const ushort* a0 = pairB + (size_t)(r0 + lr) * L2_ + lg * 8;
    const ushort* a1 = a0 + 16 * L2_;
    const ushort* b0 = WtB   + (size_t)(c0 + lr) * L2_ + lg * 8;
    const ushort* b1 = b0 + 16 * L2_;

#pragma unroll 4
    for (int k0 = 0; k0 < L2_; k0 += 32) {
        const bf16x8 av0 = *reinterpret_cast<const bf16x8*>(a0 + k0);
        const bf16x8 av1 = *reinterpret_cast<const bf16x8*>(a1 + k0);
        const bf16x8 bv0 = *reinterpret_cast<const bf16x8*>(b0 + k0);
        const bf16x8 bv1 = *reinterpret_cast<const bf16x8*>(b1 + k0);
        acc00 = __builtin_amdgcn_mfma_f32_16x16x32_bf16(av0, bv0, acc00, 0, 0, 0);
        acc01 = __builtin_amdgcn_mfma_f32_16x16x32_bf16(av0, bv1, acc01, 0, 0, 0);
        acc10 = __builtin_amdgcn_mfma_f32_16x16x32_bf16(av1, bv0, acc10, 0, 0, 0);
        acc11 = __builtin_amdgcn_mfma_f32_16x16x32_bf16(av1, bv1, acc11, 0, 0, 0);
    }

    const float bj0 = bias[c0 + lr];
    const float bj1 = bias[c0 + 16 + lr];
#pragma unroll
    for (int q = 0; q < 4; ++q) {
        const size_t rA = (size_t)(r0 + lg * 4 + q) * H_;
        const size_t rB = (size_t)(r0 + 16 + lg * 4 + q) * H_;
        alias_out[rA + c0 + lr]      = acc00[q] + bj0;
        alias_out[rA + c0 + 16 + lr] = acc01[q] + bj1;
        alias_out[rB + c0 + lr]      = acc10[q] + bj0;
        alias_out[rB + c0 + 16 + lr] = acc11[q] + bj1;
    }
}

// ---------------------------------------------------------------------------
// Fallback f32 vector GEMM (used only if ws is too small for the bf16 path).
// ---------------------------------------------------------------------------
__global__ __launch_bounds__(256) void span_gemm_kernel(
    const float* __restrict__ sent,
    const int*   __restrict__ sidx,
    const int*   __restrict__ eidx,
    const float* __restrict__ W,
    const float* __restrict__ bias,
    float*       __restrict__ alias_out) {

    __shared__ float As[16][64];
    __shared__ float Bs[16][64];
    __shared__ int   offS[64];
    __shared__ int   offE[64];

    const int tid = threadIdx.x;
    const int bm0 = blockIdx.y * 64;
    const int h0  = blockIdx.x * 64;

    if (tid < 64) {
        const int bm = bm0 + tid;
        const int b  = bm / M_;
        const int si = sidx[bm];
        const int ei = eidx[bm];
        offS[tid] = (si < 0) ? -1 : (b * N_ + si) * L_;
        offE[tid] = (ei < 0) ? -1 : (b * N_ + ei) * L_;
    }
    __syncthreads();

    float acc[4][4] = {};
    const int ar  = tid >> 2;
    const int akq = (tid & 3) * 4;
    const int bkr = tid >> 4;
    const int bc  = (tid & 15) * 4;
    const int ty  = tid >> 4;
    const int tx  = tid & 15;

    for (int l0 = 0; l0 < L2_; l0 += 16) {
        {
            const int lb = l0 + akq;
            int off, ll;
            if (lb < L_) { off = offS[ar]; ll = lb; }
            else         { off = offE[ar]; ll = lb - L_; }
            float4 v;
            if (off < 0) v = make_float4(0.f, 0.f, 0.f, 0.f);
            else         v = *reinterpret_cast<const float4*>(sent + off + ll);
            As[akq + 0][ar] = v.x;  As[akq + 1][ar] = v.y;
            As[akq + 2][ar] = v.z;  As[akq + 3][ar] = v.w;
        }
        {
            const float4 v = *reinterpret_cast<const float4*>(
                W + (size_t)(l0 + bkr) * H_ + h0 + bc);
            *reinterpret_cast<float4*>(&Bs[bkr][bc]) = v;
        }
        __syncthreads();
#pragma unroll
        for (int k = 0; k < 16; ++k) {
            const float4 av = *reinterpret_cast<const float4*>(&As[k][ty * 4]);
            const float4 bv = *reinterpret_cast<const float4*>(&Bs[k][tx * 4]);
            acc[0][0] += av.x * bv.x; acc[0][1] += av.x * bv.y;
            acc[0][2] += av.x * bv.z; acc[0][3] += av.x * bv.w;
            acc[1][0] += av.y * bv.x; acc[1][1] += av.y * bv.y;
            acc[1][2] += av.y * bv.z; acc[1][3] += av.y * bv.w;
            acc[2][0] += av.z * bv.x; acc[2][1] += av.z * bv.y;
            acc[2][2] += av.z * bv.z; acc[2][3] += av.z * bv.w;
            acc[3][0] += av.w * bv.x; acc[3][1] += av.w * bv.y;
            acc[3][2] += av.w * bv.z; acc[3][3] += av.w * bv.w;
        }
        __syncthreads();
    }

    const float4 bb = *reinterpret_cast<const float4*>(bias + h0 + tx * 4);
#pragma unroll
    for (int i = 0; i < 4; ++i) {
        const int bm = bm0 + ty * 4 + i;
        const float4 o = make_float4(acc[i][0] + bb.x, acc[i][1] + bb.y,
                                     acc[i][2] + bb.z, acc[i][3] + bb.w);
        *reinterpret_cast<float4*>(alias_out + (size_t)bm * H_ + h0 + tx * 4) = o;
    }
}

// ---------------------------------------------------------------------------
// Kernel 2: masked ent copy + scores.  One block per (b,m,k) row of H=1024.
// ---------------------------------------------------------------------------
__global__ __launch_bounds__(256) void ent_scores_kernel(
    const float* __restrict__ ent_in,
    const float* __restrict__ alias,
    const void*  __restrict__ mask,
    const int*   __restrict__ flag,
    float*       __restrict__ scores,
    float*       __restrict__ ent_out) {

    const int bmk = blockIdx.x;
    const int tid = threadIdx.x;

    const bool byte_packed = (*flag != 0);
    bool masked;
    if (byte_packed) masked = ((const uint8_t*)mask)[bmk] != 0;
    else             masked = ((const uint32_t*)mask)[bmk] != 0u;

    const size_t rowo = (size_t)bmk * H_;
    float p = 0.f;
    float4 e;
    if (masked) {
        e = make_float4(0.f, 0.f, 0.f, 0.f);
    } else {
        e = *reinterpret_cast<const float4*>(ent_in + rowo + tid * 4);
        const int bm = bmk / K_;
        const float4 a = *reinterpret_cast<const float4*>(
            alias + (size_t)bm * H_ + tid * 4);
        p = a.x * e.x + a.y * e.y + a.z * e.z + a.w * e.w;
    }
    *reinterpret_cast<float4*>(ent_out + rowo + tid * 4) = e;

#pragma unroll
    for (int off = 32; off > 0; off >>= 1) p += __shfl_down(p, off);
    __shared__ float red[4];
    if ((tid & 63) == 0) red[tid >> 6] = p;
    __syncthreads();
    if (tid == 0) scores[bmk] = red[0] + red[1] + red[2] + red[3];
}

// ---------------------------------------------------------------------------
extern "C" void kernel_launch(void* const* d_in, const int* in_sizes, int n_in,
                              void* d_out, int out_size, void* d_ws, size_t ws_size,
                              hipStream_t stream) {
    const float* sent = (const float*)d_in[0];   // (B,N,L) f32
    const float* ent  = (const float*)d_in[1];   // (B,M,K,H) f32
    const void*  mask = d_in[2];                 // (B,M,K) bool
    const int*   sidx = (const int*)d_in[3];     // (B,M) i32
    const int*   eidx = (const int*)d_in[4];     // (B,M) i32
    const float* W    = (const float*)d_in[5];   // (2L,H) f32
    const float* bias = (const float*)d_in[6];   // (H,) f32

    float* scores  = (float*)d_out;                          // B*M*K
    float* ent_out = (float*)d_out + (size_t)BMK_;           // B*M*K*H

    // ws layout: [0,256) flag | alias f32 (6.29 MB) | pairB bf16 (4.72 MB)
    //            | WtB bf16 (3.15 MB)
    const size_t ALIAS_B = (size_t)BM_ * H_ * 4;
    const size_t PAIR_B  = (size_t)BM_ * L2_ * 2;
    const size_t WT_B    = (size_t)H_ * L2_ * 2;

    int*    flag  = (int*)d_ws;
    float*  alias = (float*)((char*)d_ws + 256);
    ushort* pairB = (ushort*)((char*)d_ws + 256 + ALIAS_B);
    ushort* WtB   = (ushort*)((char*)d_ws + 256 + ALIAS_B + PAIR_B);

    detect_mask_kernel<<<1, 256, 0, stream>>>((const uint32_t*)mask, flag);

    if (ws_size >= 256 + ALIAS_B + PAIR_B + WT_B) {
        gather_pair_bf16<<<BM_, 192, 0, stream>>>(sent, sidx, eidx, pairB);
        wt_bf16_kernel<<<dim3(L2_ / 32, H_ / 32), 256, 0, stream>>>(W, WtB);
        mfma_span_gemm<<<dim3(H_ / 32, BM_ / 32), 64, 0, stream>>>(
            pairB, WtB, bias, alias);
    } else {
        span_gemm_kernel<<<dim3(H_ / 64, BM_ / 64), 256, 0, stream>>>(
            sent, sidx, eidx, W, bias, alias);
    }

    ent_scores_kernel<<<BMK_, 256, 0, stream>>>(
        ent, alias, mask, flag, scores, ent_out);
}